// Round 1
// baseline (577.884 us; speedup 1.0000x reference)
//
#include <hip/hip_runtime.h>
#include <hip/hip_bf16.h>
#include <math.h>

#define BB 8
#define LL 2048
#define LQ 512             // quarter sequence (recurrence runs in 4 passes)
#define DD 128

// ---------------------------------------------------------------------------
// DPP helpers: full-rate VALU cross-lane adds (no LDS in the serial chain).
// ---------------------------------------------------------------------------
template <int CTRL>
__device__ __forceinline__ float dpp_add(float x) {
    int xi = __float_as_int(x);
    int yi = __builtin_amdgcn_update_dpp(xi, xi, CTRL, 0xF, 0xF, false);
    return x + __int_as_float(yi);
}
// 16-lane allreduce: ^1, ^2 (quad_perm), ^:8 (half_mirror), ^:16 (mirror)
__device__ __forceinline__ float allreduce16(float p) {
    p = dpp_add<0xB1>(p);
    p = dpp_add<0x4E>(p);
    p = dpp_add<0x141>(p);
    p = dpp_add<0x140>(p);
    return p;
}
// finish a 64-lane allreduce from 16-lane row sums: ^16 via ds_swizzle
// (BitMode xor=16 -> 0x401F), then ^32 via shfl. All lanes end with the total.
__device__ __forceinline__ float red_tail(float p) {
    p += __int_as_float(__builtin_amdgcn_ds_swizzle(__float_as_int(p), 0x401F));
    p += __shfl_xor(p, 32);
    return p;
}

// ---------------------------------------------------------------------------
// C[M,O] = X @ W[O,128]^T, optional sigmoid. X rows addressed with (batch,
// quarter) strides so the scattered oc layout works: row m -> b=m>>11,
// t=m&2047, q=t>>9, tl=t&511; addr = X + b*sB + q*sQ + tl*ldx.
// ---------------------------------------------------------------------------
__global__ __launch_bounds__(256) void gemm_kernel(
    const float* __restrict__ X, long ldx, long sB, long sQ,
    const float* __restrict__ W,
    float* __restrict__ C, int ldc,
    int applySig)
{
    __shared__ float Xs[32 * 132];
    __shared__ float Ws[64 * 132];
    const int tid = threadIdx.x;
    const int m0 = blockIdx.x * 32;
    const int o0 = blockIdx.y * 64;
    {
        int row = tid >> 3, cg = tid & 7;
        int m = m0 + row;
        int b = m >> 11, t = m & 2047, qq = t >> 9, tl = t & 511;
        const float* src = X + (size_t)b * sB + (size_t)qq * sQ
                             + (size_t)tl * ldx + cg * 16;
        float* dst = Xs + row * 132 + cg * 16;
#pragma unroll
        for (int u = 0; u < 4; ++u)
            *(float4*)(dst + 4 * u) = *(const float4*)(src + 4 * u);
    }
    {
        int o = tid >> 2, cg = tid & 3;
        const float* src = W + (size_t)(o0 + o) * 128 + cg * 32;
        float* dst = Ws + o * 132 + cg * 32;
#pragma unroll
        for (int u = 0; u < 8; ++u)
            *(float4*)(dst + 4 * u) = *(const float4*)(src + 4 * u);
    }
    __syncthreads();
    const int tx = tid & 31, ty = tid >> 5;
    float acc[4][2] = {};
    const float* xb = Xs + (ty * 4) * 132;
    const float* wb = Ws + (tx * 2) * 132;
    for (int k0 = 0; k0 < 128; k0 += 4) {
        float4 xr[4], wr[2];
#pragma unroll
        for (int r = 0; r < 4; ++r) xr[r] = *(const float4*)(xb + r * 132 + k0);
#pragma unroll
        for (int cc = 0; cc < 2; ++cc) wr[cc] = *(const float4*)(wb + cc * 132 + k0);
#pragma unroll
        for (int r = 0; r < 4; ++r)
#pragma unroll
            for (int cc = 0; cc < 2; ++cc) {
                acc[r][cc] += xr[r].x * wr[cc].x + xr[r].y * wr[cc].y
                            + xr[r].z * wr[cc].z + xr[r].w * wr[cc].w;
            }
    }
#pragma unroll
    for (int r = 0; r < 4; ++r)
#pragma unroll
        for (int cc = 0; cc < 2; ++cc) {
            float v = acc[r][cc];
            if (applySig) v = 1.0f / (1.0f + __expf(-v));
            C[(size_t)(m0 + ty * 4 + r) * ldc + o0 + tx * 2 + cc] = v;
        }
}

// ---------------------------------------------------------------------------
// Depthwise conv(K=3) + sigmoid + L2-norm for q,k; packs the recurrence
// stream TIME-BLOCKED (TB=4): for batch b, block tb=t>>2, ti=t&3:
//   pack2[(b*512 + tb)*2560 + (o*128 + d)*4 + ti],  o in {k,m,a,q,v}
// so one float4 load in the recurrence yields 4 timesteps of one scalar.
// ---------------------------------------------------------------------------
__global__ __launch_bounds__(256) void convnorm_kernel(
    const float* __restrict__ qkv,
    const float* __restrict__ qw, const float* __restrict__ qb,
    const float* __restrict__ kw, const float* __restrict__ kb,
    const float* __restrict__ ab,
    float* __restrict__ pack)
{
    const int tid = threadIdx.x;
    const int lane = tid & 63;
    const int wid = tid >> 6;
    const int m = blockIdx.x * 4 + wid;     // b*L + l
    const int l = m & (LL - 1);
    const int b = m >> 11;
    const int d0 = lane * 2;
    float yq0 = qb[d0], yq1 = qb[d0 + 1];
    float yk0 = kb[d0], yk1 = kb[d0 + 1];
#pragma unroll
    for (int tau = 0; tau < 3; ++tau) {
        int lp = l + tau - 1;
        if (lp >= 0 && lp < LL) {
            const float* base = qkv + (size_t)(m + tau - 1) * 512;
            yq0 += base[d0]       * qw[d0 * 3 + tau];
            yq1 += base[d0 + 1]   * qw[(d0 + 1) * 3 + tau];
            yk0 += base[128 + d0]     * kw[d0 * 3 + tau];
            yk1 += base[128 + d0 + 1] * kw[(d0 + 1) * 3 + tau];
        }
    }
    yq0 = 1.0f / (1.0f + __expf(-yq0));
    yq1 = 1.0f / (1.0f + __expf(-yq1));
    yk0 = 1.0f / (1.0f + __expf(-yk0));
    yk1 = 1.0f / (1.0f + __expf(-yk1));
    float sq = yq0 * yq0 + yq1 * yq1;
    float sk = yk0 * yk0 + yk1 * yk1;
#pragma unroll
    for (int msk = 1; msk <= 32; msk <<= 1) {
        sq += __shfl_xor(sq, msk);
        sk += __shfl_xor(sk, msk);
    }
    float rq = 1.0f / fmaxf(sqrtf(sq), 1e-12f);
    float rk = 1.0f / fmaxf(sqrtf(sk), 1e-12f);
    float k0n = yk0 * rk, k1n = yk1 * rk;
    float a0 = ab[(size_t)m * 256 + d0];
    float a1 = ab[(size_t)m * 256 + d0 + 1];
    float b0 = ab[(size_t)m * 256 + 128 + d0];
    float b1 = ab[(size_t)m * 256 + 128 + d0 + 1];
    float v0 = qkv[(size_t)m * 512 + 256 + d0];
    float v1 = qkv[(size_t)m * 512 + 256 + d0 + 1];
    float* P = pack + ((size_t)b * 512 + (l >> 2)) * 2560 + (l & 3);
    P[d0 * 4]              = k0n;      P[(d0 + 1) * 4]        = k1n;
    P[512 + d0 * 4]        = b0 * k0n; P[512 + (d0 + 1) * 4]  = b1 * k1n;
    P[1024 + d0 * 4]       = a0;       P[1024 + (d0 + 1) * 4] = a1;
    P[1536 + d0 * 4]       = yq0 * rq; P[1536 + (d0 + 1) * 4] = yq1 * rq;
    P[2048 + d0 * 4]       = v0;       P[2048 + (d0 + 1) * 4] = v1;
}

// ---------------------------------------------------------------------------
// Block lookahead prep (chunked WY form of the delta rule, T=4).
// Per (b, tb) block with in-block steps tau=0..3:
//   sk_tau = S_{-1}.ktil_tau + sum_{s<tau} [ v_s*G_{s,tau} - sk_s*H_{s,tau} ]
//   ktil_tau = (prod_{r<tau} a_r) o k_tau         (overwrites pack's k slot)
//   G_{s,t}  = (prod_{s<r<t} a_r o m_s) . k_t     (stream-only scalars)
//   H_{s,t}  = (prod_{s<r<t} a_r o a_s o m_s) . k_t
// 12 scalars per block -> gh[(b*512+tb)*16 + {0..11}]:
//   {G01,H01,G02,H02, G03,H03,G12,H12, G13,H13,G23,H23}
// One wave per block, 4 waves/WG, grid 1024.
// ---------------------------------------------------------------------------
__global__ __launch_bounds__(256) void blockprep_kernel(
    float* __restrict__ pack, float* __restrict__ gh)
{
    const int lane = threadIdx.x & 63;
    const int w = threadIdx.x >> 6;
    const int tbid = blockIdx.x * 4 + w;          // b*512 + tb, 0..4095
    const int j0 = lane * 2;
    float* P = pack + (size_t)tbid * 2560;
    float4 kc[2], mc[2], ac[2];
    kc[0] = *(const float4*)(P + j0 * 4);
    kc[1] = *(const float4*)(P + j0 * 4 + 4);
    mc[0] = *(const float4*)(P + 512 + j0 * 4);
    mc[1] = *(const float4*)(P + 512 + j0 * 4 + 4);
    ac[0] = *(const float4*)(P + 1024 + j0 * 4);
    ac[1] = *(const float4*)(P + 1024 + j0 * 4 + 4);
    float s[12];
#pragma unroll
    for (int i = 0; i < 12; ++i) s[i] = 0.f;
#pragma unroll
    for (int c = 0; c < 2; ++c) {
        const float k1 = kc[c].y, k2 = kc[c].z, k3 = kc[c].w;
        const float m0 = mc[c].x, m1 = mc[c].y, m2 = mc[c].z;
        const float a0 = ac[c].x, a1 = ac[c].y, a2 = ac[c].z;
        float t  = m0, ta = a0 * m0;
        s[0]  += t * k1;   s[1]  += ta * k1;      // G01, H01
        t *= a1; ta *= a1;
        s[2]  += t * k2;   s[3]  += ta * k2;      // G02, H02
        t *= a2; ta *= a2;
        s[4]  += t * k3;   s[5]  += ta * k3;      // G03, H03
        float u = m1, ua = a1 * m1;
        s[6]  += u * k2;   s[7]  += ua * k2;      // G12, H12
        u *= a2; ua *= a2;
        s[8]  += u * k3;   s[9]  += ua * k3;      // G13, H13
        s[10] += m2 * k3;  s[11] += a2 * m2 * k3; // G23, H23
        // ktilde in place (raw k used above, prefix-scaled below)
        const float p01 = a0, p012 = a0 * a1;
        kc[c].y = k1 * p01;
        kc[c].z = k2 * p012;
        kc[c].w = k3 * (p012 * a2);
    }
#pragma unroll
    for (int i = 0; i < 12; ++i)
#pragma unroll
        for (int msk = 1; msk <= 32; msk <<= 1)
            s[i] += __shfl_xor(s[i], msk);
    *(float4*)(P + j0 * 4)     = kc[0];
    *(float4*)(P + j0 * 4 + 4) = kc[1];
    if (lane == 0) {
        float* q = gh + (size_t)tbid * 16;
        float4 g0 = { s[0], s[1], s[2],  s[3]  };
        float4 g1 = { s[4], s[5], s[6],  s[7]  };
        float4 g2 = { s[8], s[9], s[10], s[11] };
        *(float4*)(q)     = g0;
        *(float4*)(q + 4) = g1;
        *(float4*)(q + 8) = g2;
    }
}

// ---------------------------------------------------------------------------
// Barrier-free delta-rule recurrence, R=1 row/wave, QUARTER sequence/call,
// CHUNKED T=4 lookahead: all 4 dots of a block computed from the block-start
// state (k slot of pack holds ktilde), their 4 reduces pipeline as
// independent chains (4 DPP + ds_swizzle^16 + shfl^32 each), then a ~6-fma
// scalar chain resolves sk0..sk3 from the precomputed G/H terms, then 4
// elementwise state updates + bf16 partial stores (no cross-lane ops).
// Reduce latency is paid once per 4 steps instead of once per step.
// Grid 1024 = BB*128 one-wave WGs -> 1 wave per SIMD chip-wide.
// Partials: bf16, pout[g][b][tl][d], g in [0,128), tl in [0,LQ).
// ---------------------------------------------------------------------------
__global__ __launch_bounds__(64, 1) void recur1_kernel(
    const float* __restrict__ pack, const float* __restrict__ ghg,
    const float* __restrict__ sin,
    __hip_bfloat16* __restrict__ pout, float* __restrict__ sout, int blk0)
{
    const int lane = threadIdx.x;
    const int b = blockIdx.x >> 7;
    const int g = blockIdx.x & 127;
    const int j0 = lane * 2;

    float SA[2];
    {
        const float* sp = sin + ((size_t)b * DD + g) * DD + j0;
        float2 t2 = *(const float2*)sp;
        SA[0] = t2.x; SA[1] = t2.y;
    }

    const float* P  = pack + ((size_t)b * 512 + blk0) * 2560;
    const float* GH = ghg  + ((size_t)b * 512 + blk0) * 16;
    __hip_bfloat16* po = pout + ((size_t)g * (BB * LQ) + (size_t)b * LQ) * DD + j0;

    // block-level double buffers (statically indexed)
    float4 ka[2][2], ma[2][2], aa[2][2], qv[2], vv[2], gA[2], gB[2], gC[2];

#define PREB(BF)                                                             \
    do {                                                                     \
        ka[BF][0] = *(const float4*)(P + j0 * 4);                            \
        ka[BF][1] = *(const float4*)(P + j0 * 4 + 4);                        \
        ma[BF][0] = *(const float4*)(P + 512 + j0 * 4);                      \
        ma[BF][1] = *(const float4*)(P + 512 + j0 * 4 + 4);                  \
        aa[BF][0] = *(const float4*)(P + 1024 + j0 * 4);                     \
        aa[BF][1] = *(const float4*)(P + 1024 + j0 * 4 + 4);                 \
        qv[BF]    = *(const float4*)(P + 1536 + g * 4);                      \
        vv[BF]    = *(const float4*)(P + 2048 + g * 4);                      \
        gA[BF]    = *(const float4*)(GH);                                    \
        gB[BF]    = *(const float4*)(GH + 4);                                \
        gC[BF]    = *(const float4*)(GH + 8);                                \
        P += 2560; GH += 16;                                                 \
        __builtin_amdgcn_sched_barrier(0);  /* pin load-issue point */       \
    } while (0)

#define UPD(BF, CMP, SK)                                                     \
    do {                                                                     \
        const float a0 = aa[BF][0].CMP, a1 = aa[BF][1].CMP;                  \
        const float m0 = ma[BF][0].CMP, m1 = ma[BF][1].CMP;                  \
        const float vg = vv[BF].CMP, qg = qv[BF].CMP;                        \
        float w0 = fmaf(-a0, SK, vg);                                        \
        SA[0] = fmaf(m0, w0, a0 * SA[0]);                                    \
        float w1 = fmaf(-a1, SK, vg);                                        \
        SA[1] = fmaf(m1, w1, a1 * SA[1]);                                    \
        __hip_bfloat162 h2;                                                  \
        h2.x = __float2bfloat16(qg * SA[0]);                                 \
        h2.y = __float2bfloat16(qg * SA[1]);                                 \
        *(__hip_bfloat162*)po = h2;                                          \
        po += DD;                                                            \
    } while (0)

#define BLOCK(BF)                                                            \
    do {                                                                     \
        float E0 = fmaf(SA[1], ka[BF][1].x, SA[0] * ka[BF][0].x);            \
        float E1 = fmaf(SA[1], ka[BF][1].y, SA[0] * ka[BF][0].y);            \
        float E2 = fmaf(SA[1], ka[BF][1].z, SA[0] * ka[BF][0].z);            \
        float E3 = fmaf(SA[1], ka[BF][1].w, SA[0] * ka[BF][0].w);            \
        E0 = allreduce16(E0); E1 = allreduce16(E1);                          \
        E2 = allreduce16(E2); E3 = allreduce16(E3);                          \
        E0 = red_tail(E0); E1 = red_tail(E1);                                \
        E2 = red_tail(E2); E3 = red_tail(E3);                                \
        const float vg0 = vv[BF].x, vg1 = vv[BF].y, vg2 = vv[BF].z;          \
        float u1 = vg0 * gA[BF].x;                                           \
        float u2 = fmaf(vg1, gB[BF].z, vg0 * gA[BF].z);                      \
        float u3 = fmaf(vg2, gC[BF].z, fmaf(vg1, gC[BF].x, vg0 * gB[BF].x)); \
        float sk0 = E0;                                                      \
        float sk1 = fmaf(-sk0, gA[BF].y, E1 + u1);                           \
        float sk2 = fmaf(-sk1, gB[BF].w, fmaf(-sk0, gA[BF].w, E2 + u2));     \
        float sk3 = fmaf(-sk2, gC[BF].w,                                     \
                    fmaf(-sk1, gC[BF].y, fmaf(-sk0, gB[BF].y, E3 + u3)));    \
        UPD(BF, x, sk0); UPD(BF, y, sk1); UPD(BF, z, sk2); UPD(BF, w, sk3);  \
    } while (0)

    PREB(0);    // block blk0
    PREB(1);    // block blk0+1
    for (int tb = 0; tb < LQ / 4; tb += 2) {
        BLOCK(0);
        PREB(0);    // blk+2 (final iters overrun into ws: values unused)
        BLOCK(1);
        PREB(1);    // blk+3
    }
#undef PREB
#undef UPD
#undef BLOCK

    {
        float* sp = sout + ((size_t)b * DD + g) * DD + j0;
        float2 o2 = {SA[0], SA[1]};
        *(float2*)sp = o2;
    }
}

// ---------------------------------------------------------------------------
// oc(quarter) = silu(sum_{g<128} pout[g])  bf16 -> fp32. Writes into the
// DEAD quarter-band of pack:
//   oc(b,q,tl,d) = ocbase[b*512*2560 + q*128*2560 + tl*128 + d]
// (tl*128+d < 65536 < 327680 = quarter band size: fits.)
// ---------------------------------------------------------------------------
__global__ __launch_bounds__(256) void combine_silu_kernel(
    const ushort* __restrict__ pout, float* __restrict__ ocbase, int q)
{
    const size_t NQ = (size_t)BB * LQ * DD;   // 524288 elems per slice
    size_t idx = ((size_t)blockIdx.x * 256 + threadIdx.x) * 4;
    float s0 = 0, s1 = 0, s2 = 0, s3 = 0;
#pragma unroll 8
    for (int gi = 0; gi < 128; ++gi) {
        uint2 u = *(const uint2*)(pout + gi * NQ + idx);
        s0 += __uint_as_float((u.x & 0xffffu) << 16);
        s1 += __uint_as_float(u.x & 0xffff0000u);
        s2 += __uint_as_float((u.y & 0xffffu) << 16);
        s3 += __uint_as_float(u.y & 0xffff0000u);
    }
    float4 r;
    r.x = s0 / (1.0f + __expf(-s0));
    r.y = s1 / (1.0f + __expf(-s1));
    r.z = s2 / (1.0f + __expf(-s2));
    r.w = s3 / (1.0f + __expf(-s3));
    size_t b = idx >> 16;                 // / (LQ*DD)
    size_t rem = idx & ((size_t)LQ * DD - 1);
    float* dst = ocbase + b * (512ull * 2560) + (size_t)q * (128ull * 2560) + rem;
    *(float4*)dst = r;
}

// ---------------------------------------------------------------------------
// d_out = y * rsqrt(mean(y^2)+1e-6) * rms_w + residual. One wave per (b,l).
// ---------------------------------------------------------------------------
__global__ __launch_bounds__(256) void rms_res_kernel(
    const float* __restrict__ y, const float* __restrict__ res,
    const float* __restrict__ rmsw, float* __restrict__ out)
{
    const int tid = threadIdx.x;
    const int lane = tid & 63;
    const int wid = tid >> 6;
    const int m = blockIdx.x * 4 + wid;
    const int d0 = lane * 2;
    size_t o = (size_t)m * DD + d0;
    float2 yv = *(const float2*)(y + o);
    float ss = yv.x * yv.x + yv.y * yv.y;
#pragma unroll
    for (int msk = 1; msk <= 32; msk <<= 1) ss += __shfl_xor(ss, msk);
    float r = rsqrtf(ss * (1.0f / 128.0f) + 1e-6f);
    float2 rv = *(const float2*)(res + o);
    out[o]     = yv.x * r * rmsw[d0]     + rv.x;
    out[o + 1] = yv.y * r * rmsw[d0 + 1] + rv.y;
}

// ---------------------------------------------------------------------------
// Workspace (176,160,768 B total — unchanged footprint):
//   [0, 41.9MB)   pack2 blocked [B,512,2560] fp32. After each quarter's
//                 recurrence that quarter's band is dead -> combine -> oc.
//   [41.9MB, +134.2MB) poreg:
//      phase 1:  qkv [M,512] + abv [M,256]
//      phase 2:  pout bf16, 128 slices x [B,LQ,D]  (reused for 4 quarters)
//      phase 3:  res [M,128] + yb [M,128]
// Inter-pass state lives in sfin (inside d_out): written pass q, read q+1.
// G/H lookahead scalars (256KB) live at the BASE of d_out's `out` region:
// read only by recur passes, overwritten at the very end by rms_res.
// ---------------------------------------------------------------------------
extern "C" void kernel_launch(void* const* d_in, const int* in_sizes, int n_in,
                              void* d_out, int out_size, void* d_ws, size_t ws_size,
                              hipStream_t stream)
{
    const float* x      = (const float*)d_in[0];
    const float* state  = (const float*)d_in[1];
    const float* W_in   = (const float*)d_in[2];
    const float* W_gate = (const float*)d_in[3];
    const float* W_out  = (const float*)d_in[4];
    const float* W_res  = (const float*)d_in[5];
    const float* qcw    = (const float*)d_in[6];
    const float* qcb    = (const float*)d_in[7];
    const float* kcw    = (const float*)d_in[8];
    const float* kcb    = (const float*)d_in[9];
    const float* rmsw   = (const float*)d_in[10];
    float* out  = (float*)d_out;
    float* sfin = out + (size_t)BB * LL * DD;
    float* ghs  = out;                           // 256KB, dead until rms_res

    const size_t M = (size_t)BB * LL;            // 16384
    char* base = (char*)d_ws;
    const size_t PACK_BYTES = M * 640 * 4;       // 41.9 MB
    float* pack = (float*)base;
    char*  poreg = base + PACK_BYTES;
    float* qkv = (float*)poreg;                              // phase 1
    float* abv = (float*)(poreg + M * 512 * 4);              // phase 1
    __hip_bfloat16* po = (__hip_bfloat16*)poreg;             // phase 2
    float* res = (float*)poreg;                              // phase 3 (over po)
    float* yb  = (float*)(poreg + M * DD * 4);               // phase 3

    dim3 blk(256);
    // qkv = x @ W_in^T  [M,512]
    gemm_kernel<<<dim3(M / 32, 8), blk, 0, stream>>>(
        x, 128, 2048L * 128, 512L * 128, W_in, qkv, 512, 0);
    // alpha/beta = sigmoid(gate @ W_gate^T) [M,256]
    gemm_kernel<<<dim3(M / 32, 4), blk, 0, stream>>>(
        qkv + 384, 512, 2048L * 512, 512L * 512, W_gate, abv, 256, 1);
    // conv + sigmoid + l2norm + blocked pack stream [k|m|alpha|q|v] x TB=4
    convnorm_kernel<<<dim3(M / 4), blk, 0, stream>>>(qkv, qcw, qcb, kcw, kcb, abv, pack);
    // chunked-lookahead prep: k -> ktilde in place, G/H scalars -> ghs
    blockprep_kernel<<<dim3(1024), blk, 0, stream>>>(pack, ghs);
    // recurrence in 4 quarter passes; state relayed through sfin
    for (int q = 0; q < 4; ++q) {
        const float* sin = (q == 0) ? state : sfin;
        recur1_kernel<<<dim3(BB * 128), dim3(64), 0, stream>>>(
            pack, ghs, sin, po, sfin, q * 128);
        combine_silu_kernel<<<dim3(512), blk, 0, stream>>>(
            (const ushort*)po, pack, q);
    }
    // residual = x @ W_res^T  (po region dead after last combine)
    gemm_kernel<<<dim3(M / 32, 2), blk, 0, stream>>>(
        x, 128, 2048L * 128, 512L * 128, W_res, res, 128, 0);
    // y = oc @ W_out^T   (oc scattered in pack: sB=512*2560, sQ=128*2560)
    gemm_kernel<<<dim3(M / 32, 2), blk, 0, stream>>>(
        pack, 128, 512L * 2560, 128L * 2560, W_out, yb, 128, 0);
    // RMS + residual -> d_out
    rms_res_kernel<<<dim3(M / 4), blk, 0, stream>>>(yb, res, rmsw, out);
}